// Round 8
// baseline (312.748 us; speedup 1.0000x reference)
//
#include <hip/hip_runtime.h>
#include <math.h>
#include <stdint.h>

#define C        128
#define KCODES   1024
#define KHALF    512                  // codes per wave-group
#define TPB      512                  // 8 waves: group A = waves 0-3, group B = 4-7
#define ROWS_PB  128                  // rows per block
#define NCHUNK   64                   // codes per LDS chunk
#define NCHUNKS_H (KHALF / NCHUNK)    // 8 chunks per group
#define BSTRIDE  272                  // padded row stride (bytes) = 128*2 + 16
#define BHALF    (NCHUNK * BSTRIDE)   // byte offset of the LO plane within a buffer
#define BUFB     (2 * BHALF)          // one group's B buffer (hi+lo) = 34816 B
#define EPS_TRIG 0.25f

typedef __attribute__((ext_vector_type(8))) short bf16x8_t;
typedef __attribute__((ext_vector_type(4))) float f32x4_t;

static __device__ __forceinline__ uint32_t bf16_rne(float f) {
    uint32_t u = __float_as_uint(f);
    return (u + 0x7FFFu + ((u >> 16) & 1u)) >> 16;
}
static __device__ __forceinline__ float bf16_hi_f(float f) {
    return __uint_as_float(bf16_rne(f) << 16);
}

// ============================================================================
// Single-launch, 8-wave kernel with IN-BLOCK K-split:
//   waves 0-3 scan codes [0,512), waves 4-7 scan [512,1024), same 128 rows.
//   - Per-wave layout/numerics identical to the R4-validated K-split partial
//     (32 rows/wave, chunked LDS staging, inline fp32->bf16 hi/lo convert).
//   - Occupancy: LDS 74.75KB -> 2 blocks/CU, grid 512 fully resident ->
//     16 waves/CU (4/SIMD), 2x the R7 kernel. (R4 proved the loop scales
//     with blocks/CU; R5 proved cross-block coordination is catastrophic --
//     this gets the occupancy without leaving the block.)
//   - Half-merge (R4-validated comparator) + finalize + gather in-block.
// ============================================================================
#define SLOTS(OP) OP(0,0) OP(0,1) OP(0,2) OP(0,3) OP(1,0) OP(1,1) OP(1,2) OP(1,3)
#define MFMA_BF16 __builtin_amdgcn_mfma_f32_16x16x32_bf16

__global__ __launch_bounds__(TPB, 4)
void vq_fused_kernel(const float* __restrict__ x,
                     const float* __restrict__ cb,
                     float* __restrict__ out_codes,
                     float* __restrict__ out_fidx,
                     float* __restrict__ out_idx,
                     float* __restrict__ out_dist,
                     int rows)
{
    __shared__ __align__(16) uint8_t s_buf[2 * BUFB];    // 69632 B; group A half is also A-stage area
    __shared__ float s_cq[2][NCHUNK];
    __shared__ float s_v1h[2][ROWS_PB], s_v2h[2][ROWS_PB];
    __shared__ int   s_k1h[2][ROWS_PB], s_k2h[2][ROWS_PB];
    __shared__ int   s_k1f[ROWS_PB];

    const int t    = threadIdx.x;
    const int lane = t & 63;
    const int w    = t >> 6;       // wave 0..7
    const int kh   = w >> 2;       // code-half 0/1
    const int wg   = w & 3;        // wave-in-group 0..3
    const int tg   = t & 255;      // thread-in-group 0..255
    const int ln   = lane & 15;
    const int quad = lane >> 4;
    const int rowblock = blockIdx.x * ROWS_PB;
    const int kh0      = kh * KHALF;

    // ---- stage x tile -> bf16 HI in s_buf (padded row-major), all 512 threads ----
    #pragma unroll 4
    for (int i = 0; i < 8; ++i) {
        int fid = t + i * TPB;            // float4 id in tile (4096)
        int row = fid >> 5;               // 0..127
        int kq  = fid & 31;               // float4 within row
        int grow = rowblock + row;
        grow = grow < rows ? grow : rows - 1;
        float4 v = ((const float4*)x)[(size_t)grow * 32 + kq];
        uint32_t p0 = bf16_rne(v.x) | (bf16_rne(v.y) << 16);
        uint32_t p1 = bf16_rne(v.z) | (bf16_rne(v.w) << 16);
        *(uint2*)(s_buf + row * BSTRIDE + kq * 8) = make_uint2(p0, p1);
    }
    __syncthreads();

    // ---- A-hi fragments -> registers (waves 0&4 share rows 0-31, etc.) ----
    const int arow0 = (wg * 32 + ln) * BSTRIDE;        // rowgroup 0
    const int arow1 = (wg * 32 + 16 + ln) * BSTRIDE;   // rowgroup 1
    bf16x8_t ah00, ah01, ah02, ah03, ah10, ah11, ah12, ah13;
    ah00 = *(const bf16x8_t*)(s_buf + arow0 + 0 * 64 + quad * 16);
    ah01 = *(const bf16x8_t*)(s_buf + arow0 + 1 * 64 + quad * 16);
    ah02 = *(const bf16x8_t*)(s_buf + arow0 + 2 * 64 + quad * 16);
    ah03 = *(const bf16x8_t*)(s_buf + arow0 + 3 * 64 + quad * 16);
    ah10 = *(const bf16x8_t*)(s_buf + arow1 + 0 * 64 + quad * 16);
    ah11 = *(const bf16x8_t*)(s_buf + arow1 + 1 * 64 + quad * 16);
    ah12 = *(const bf16x8_t*)(s_buf + arow1 + 2 * 64 + quad * 16);
    ah13 = *(const bf16x8_t*)(s_buf + arow1 + 3 * 64 + quad * 16);
    __syncthreads();

    // ---- stage x tile -> bf16 LO ----
    #pragma unroll 4
    for (int i = 0; i < 8; ++i) {
        int fid = t + i * TPB;
        int row = fid >> 5;
        int kq  = fid & 31;
        int grow = rowblock + row;
        grow = grow < rows ? grow : rows - 1;
        float4 v = ((const float4*)x)[(size_t)grow * 32 + kq];
        uint32_t p0 = bf16_rne(v.x - bf16_hi_f(v.x)) | (bf16_rne(v.y - bf16_hi_f(v.y)) << 16);
        uint32_t p1 = bf16_rne(v.z - bf16_hi_f(v.z)) | (bf16_rne(v.w - bf16_hi_f(v.w)) << 16);
        *(uint2*)(s_buf + row * BSTRIDE + kq * 8) = make_uint2(p0, p1);
    }
    __syncthreads();

    bf16x8_t al00, al01, al02, al03, al10, al11, al12, al13;
    al00 = *(const bf16x8_t*)(s_buf + arow0 + 0 * 64 + quad * 16);
    al01 = *(const bf16x8_t*)(s_buf + arow0 + 1 * 64 + quad * 16);
    al02 = *(const bf16x8_t*)(s_buf + arow0 + 2 * 64 + quad * 16);
    al03 = *(const bf16x8_t*)(s_buf + arow0 + 3 * 64 + quad * 16);
    al10 = *(const bf16x8_t*)(s_buf + arow1 + 0 * 64 + quad * 16);
    al11 = *(const bf16x8_t*)(s_buf + arow1 + 1 * 64 + quad * 16);
    al12 = *(const bf16x8_t*)(s_buf + arow1 + 2 * 64 + quad * 16);
    al13 = *(const bf16x8_t*)(s_buf + arow1 + 3 * 64 + quad * 16);
    __syncthreads();

    // ---- per-lane top-2 state (8 row-slots) ----
#define DECL(g,r) float v1_##g##r = INFINITY, v2_##g##r = INFINITY; int k1_##g##r = 0, k2_##g##r = 0;
    SLOTS(DECL)
#undef DECL

    uint8_t* const gbuf = s_buf + kh * BUFB;   // this group's B buffer

    #pragma unroll 1
    for (int chn = 0; chn < NCHUNKS_H; ++chn) {
        const int kbase = kh0 + chn * NCHUNK;
        // ---- stage B chunk from RAW fp32 codebook (group-local, 256 threads):
        //      inline bf16 hi/lo convert (bit-identical exprs, R5/R7-validated)
        //      + coarse ||c||^2 via 16-lane tree reduce (selection-only). ----
        #pragma unroll
        for (int i = 0; i < 4; ++i) {
            int uid  = tg + i * 256;         // slot id (1024): code*16 + g
            int code = uid >> 4, g = uid & 15;
            const float4* src = (const float4*)(cb + (size_t)(kbase + code) * C) + g * 2;
            float4 v0 = src[0], v1 = src[1];
            uint32_t h0 = bf16_rne(v0.x) | (bf16_rne(v0.y) << 16);
            uint32_t h1 = bf16_rne(v0.z) | (bf16_rne(v0.w) << 16);
            uint32_t h2 = bf16_rne(v1.x) | (bf16_rne(v1.y) << 16);
            uint32_t h3 = bf16_rne(v1.z) | (bf16_rne(v1.w) << 16);
            uint32_t l0 = bf16_rne(v0.x - bf16_hi_f(v0.x)) | (bf16_rne(v0.y - bf16_hi_f(v0.y)) << 16);
            uint32_t l1 = bf16_rne(v0.z - bf16_hi_f(v0.z)) | (bf16_rne(v0.w - bf16_hi_f(v0.w)) << 16);
            uint32_t l2 = bf16_rne(v1.x - bf16_hi_f(v1.x)) | (bf16_rne(v1.y - bf16_hi_f(v1.y)) << 16);
            uint32_t l3 = bf16_rne(v1.z - bf16_hi_f(v1.z)) | (bf16_rne(v1.w - bf16_hi_f(v1.w)) << 16);
            *(uint4*)(gbuf + code * BSTRIDE + g * 16)          = make_uint4(h0, h1, h2, h3);
            *(uint4*)(gbuf + BHALF + code * BSTRIDE + g * 16)  = make_uint4(l0, l1, l2, l3);
            float ps = ((v0.x * v0.x + v0.y * v0.y) + (v0.z * v0.z + v0.w * v0.w))
                     + ((v1.x * v1.x + v1.y * v1.y) + (v1.z * v1.z + v1.w * v1.w));
            ps += __shfl_xor(ps, 1, 16);
            ps += __shfl_xor(ps, 2, 16);
            ps += __shfl_xor(ps, 4, 16);
            ps += __shfl_xor(ps, 8, 16);
            if (g == 0) s_cq[kh][code] = ps;
        }
        __syncthreads();

        const uint8_t* bbase = gbuf + (size_t)ln * BSTRIDE + quad * 16;
        #pragma unroll
        for (int ct = 0; ct < 4; ++ct) {
            const uint8_t* bh_p = bbase + (size_t)ct * 16 * BSTRIDE;
            const uint8_t* bl_p = bh_p + BHALF;
            f32x4_t acc0 = {0.f, 0.f, 0.f, 0.f};
            f32x4_t acc1 = {0.f, 0.f, 0.f, 0.f};
#define KSTEP(kk) { \
            bf16x8_t bh = *(const bf16x8_t*)(bh_p + kk * 64); \
            bf16x8_t bl = *(const bf16x8_t*)(bl_p + kk * 64); \
            acc0 = MFMA_BF16(ah0##kk, bh, acc0, 0, 0, 0); \
            acc0 = MFMA_BF16(al0##kk, bh, acc0, 0, 0, 0); \
            acc0 = MFMA_BF16(ah0##kk, bl, acc0, 0, 0, 0); \
            acc1 = MFMA_BF16(ah1##kk, bh, acc1, 0, 0, 0); \
            acc1 = MFMA_BF16(al1##kk, bh, acc1, 0, 0, 0); \
            acc1 = MFMA_BF16(ah1##kk, bl, acc1, 0, 0, 0); }
            KSTEP(0) KSTEP(1) KSTEP(2) KSTEP(3)
#undef KSTEP
            const float cqv = s_cq[kh][ct * 16 + ln];
            const int   kc  = kbase + ct * 16 + ln;
#define UPD(g,r) { \
            float s_ = fmaf(-2.0f, (g ? acc1 : acc0)[r], cqv); \
            bool c1_ = s_ < v1_##g##r; \
            bool c2_ = s_ < v2_##g##r; \
            v2_##g##r = c1_ ? v1_##g##r : (c2_ ? s_ : v2_##g##r); \
            k2_##g##r = c1_ ? k1_##g##r : (c2_ ? kc : k2_##g##r); \
            v1_##g##r = c1_ ? s_ : v1_##g##r; \
            k1_##g##r = c1_ ? kc : k1_##g##r; }
            SLOTS(UPD)
#undef UPD
        }
        __syncthreads();
    }

    // ---- butterfly merge across the 16 lanes of each col-group ----
    for (int m_ = 1; m_ <= 8; m_ <<= 1) {
#define MRG(g,r) { \
        float ov1 = __shfl_xor(v1_##g##r, m_, 16); int ok1 = __shfl_xor(k1_##g##r, m_, 16); \
        float ov2 = __shfl_xor(v2_##g##r, m_, 16); int ok2 = __shfl_xor(k2_##g##r, m_, 16); \
        if (ov1 < v1_##g##r || (ov1 == v1_##g##r && ok1 < k1_##g##r)) { \
            if (v1_##g##r < ov2 || (v1_##g##r == ov2 && k1_##g##r < ok2)) { v2_##g##r = v1_##g##r; k2_##g##r = k1_##g##r; } \
            else { v2_##g##r = ov2; k2_##g##r = ok2; } \
            v1_##g##r = ov1; k1_##g##r = ok1; \
        } else if (ov1 < v2_##g##r || (ov1 == v2_##g##r && ok1 < k2_##g##r)) { \
            v2_##g##r = ov1; k2_##g##r = ok1; \
        } }
        SLOTS(MRG)
#undef MRG
    }
    // ---- lane 0 of each col-group writes its half's per-row top-2 ----
    if (ln == 0) {
#define WRT(g,r) { int rloc = wg * 32 + g * 16 + quad * 4 + r; \
        s_v1h[kh][rloc] = v1_##g##r; s_v2h[kh][rloc] = v2_##g##r; \
        s_k1h[kh][rloc] = k1_##g##r; s_k2h[kh][rloc] = k2_##g##r; }
        SLOTS(WRT)
#undef WRT
    }
    __syncthreads();

    // ---- merge halves + finalize (threads 0..127, one per row) ----
    if (t < ROWS_PB) {
        int rowg = rowblock + t;
        const bool valid = rowg < rows;
        rowg = valid ? rowg : rows - 1;

        float av1 = s_v1h[0][t], av2 = s_v2h[0][t];
        int   ak1 = s_k1h[0][t], ak2 = s_k2h[0][t];
        float bv1 = s_v1h[1][t], bv2 = s_v2h[1][t];
        int   bk1 = s_k1h[1][t], bk2 = s_k2h[1][t];

        // merge (R4-validated comparator; half-0 indices < half-1 indices,
        // so index-tiebreak == sequential-scan order)
        float v1, v2; int k1, k2;
        if (bv1 < av1 || (bv1 == av1 && bk1 < ak1)) {
            v1 = bv1; k1 = bk1;
            if (av1 < bv2 || (av1 == bv2 && ak1 < bk2)) { v2 = av1; k2 = ak1; }
            else                                        { v2 = bv2; k2 = bk2; }
        } else {
            v1 = av1; k1 = ak1;
            if (bv1 < av2 || (bv1 == av2 && bk1 < ak2)) { v2 = bv1; k2 = bk1; }
            else                                        { v2 = av2; k2 = ak2; }
        }

        const float* xr = x + (size_t)rowg * C;

        // rs in R1 float4 order
        float sx = 0.f, sy = 0.f, sz = 0.f, sw = 0.f;
        {
            const float4* xp = (const float4*)xr;
            #pragma unroll
            for (int i = 0; i < C / 4; ++i) {
                float4 v = xp[i];
                sx += v.x * v.x; sy += v.y * v.y;
                sz += v.z * v.z; sw += v.w * v.w;
            }
        }
        const float rs = (sx + sy) + (sz + sw);

        bool switched = false;
        double qwin = 0.0;
        if (v2 - v1 < EPS_TRIG) {
            const float* c1p = cb + (size_t)k1 * C;
            const float* c2p = cb + (size_t)k2 * C;
            double dot1 = 0.0, cq1 = 0.0, dot2 = 0.0, cq2 = 0.0;
            #pragma unroll 8
            for (int c = 0; c < C; ++c) {
                const double xc  = (double)xr[c];
                const double cv1 = (double)c1p[c];
                const double cv2 = (double)c2p[c];
                dot1 += xc * cv1;  cq1 += cv1 * cv1;
                dot2 += xc * cv2;  cq2 += cv2 * cv2;
            }
            const double q1 = cq1 - 2.0 * dot1;
            const double q2 = cq2 - 2.0 * dot2;
            if (q2 < q1 || (q2 == q1 && k2 < k1)) { k1 = k2; switched = true; qwin = q2; }
        }

        // exact fp32 distance for the final k1 (R1 chain order) + inline
        // ||c_k1||^2 in the exact cbsq float4-chain order (R5/R7-validated)
        {
            const float4* c1p4 = (const float4*)(cb + (size_t)k1 * C);
            float a = 0.f;
            float qx = 0.f, qy = 0.f, qz = 0.f, qw = 0.f;
            #pragma unroll
            for (int i = 0; i < C / 4; ++i) {
                float4 cv = c1p4[i];
                float4 xv = ((const float4*)xr)[i];
                a = fmaf(xv.x, cv.x, a); a = fmaf(xv.y, cv.y, a);
                a = fmaf(xv.z, cv.z, a); a = fmaf(xv.w, cv.w, a);
                qx += cv.x * cv.x; qy += cv.y * cv.y;
                qz += cv.z * cv.z; qw += cv.w * cv.w;
            }
            float d = (rs + ((qx + qy) + (qz + qw))) - 2.f * a;
            if (switched) d = (float)((double)rs + qwin);

            if (valid) {
                out_fidx[rowg] = (float)k1;
                out_idx[rowg]  = (float)k1;
                out_dist[rowg] = d;
            }
        }
        s_k1f[t] = k1;   // final index for the gather
    }
    __syncthreads();

    // ---- gather codes: 4 threads per row (512 threads / 128 rows) ----
    {
        const int r   = t >> 2;
        const int sub = t & 3;
        const int rowg = rowblock + r;
        if (rowg < rows) {
            const int k1 = s_k1f[r];
            const float4* src = (const float4*)(cb + (size_t)k1 * C) + sub * 8;
            float4*       dst = (float4*)(out_codes + (size_t)rowg * C) + sub * 8;
            #pragma unroll
            for (int i = 0; i < 8; ++i) dst[i] = src[i];
        }
    }
}

extern "C" void kernel_launch(void* const* d_in, const int* in_sizes, int n_in,
                              void* d_out, int out_size, void* d_ws, size_t ws_size,
                              hipStream_t stream) {
    const float* x  = (const float*)d_in[0];
    const float* cb = (const float*)d_in[1];
    const int rows = in_sizes[0] / C;   // 65536

    float* out       = (float*)d_out;
    float* out_codes = out;                          // rows*C
    float* out_fidx  = out + (size_t)rows * C;       // rows
    float* out_idx   = out_fidx + rows;              // rows
    float* out_dist  = out_idx + rows;               // rows

    const int grid = (rows + ROWS_PB - 1) / ROWS_PB;   // 512
    vq_fused_kernel<<<grid, TPB, 0, stream>>>(x, cb, out_codes, out_fidx,
                                              out_idx, out_dist, rows);
}

// Round 10
// 202.534 us; speedup vs baseline: 1.5442x; 1.5442x over previous
//
#include <hip/hip_runtime.h>
#include <math.h>
#include <stdint.h>

#define C        128
#define KCODES   1024
#define KHALF    512                  // codes per wave-group
#define TPB      512                  // 8 waves: group A = waves 0-3, group B = 4-7
#define ROWS_PB  128                  // rows per block
#define NCHUNK   64                   // codes per LDS chunk
#define NCHUNKS_H (KHALF / NCHUNK)    // 8 chunks per group
#define BSTRIDE  272                  // padded row stride (bytes) = 128*2 + 16
#define BHALF    (NCHUNK * BSTRIDE)   // byte offset of the LO plane within a buffer
#define BUFB     (2 * BHALF)          // one group's B buffer (hi+lo) = 34816 B
#define EPS_TRIG 0.25f

typedef __attribute__((ext_vector_type(8))) short bf16x8_t;
typedef __attribute__((ext_vector_type(4))) float f32x4_t;

static __device__ __forceinline__ uint32_t bf16_rne(float f) {
    uint32_t u = __float_as_uint(f);
    return (u + 0x7FFFu + ((u >> 16) & 1u)) >> 16;
}
static __device__ __forceinline__ float bf16_hi_f(float f) {
    return __uint_as_float(bf16_rne(f) << 16);
}

// ============================================================================
// Single-launch, 8-wave kernel with IN-BLOCK K-split (structure validated R8:
// occupancy 43.8%, absmax 0.0).
//   R8 failed ONLY on the register budget: __launch_bounds__(512,4) capped
//   VGPRs at 64 -> ~735MB spill traffic. This loop's measured demand is
//   85-104 regs (R2/R6: 104 @ relaxed cap; R7: 84). (512,2) relaxes the cap;
//   LDS (74.75KB) already pins residency at 2 blocks/CU = 4 waves/SIMD.
// ============================================================================
#define SLOTS(OP) OP(0,0) OP(0,1) OP(0,2) OP(0,3) OP(1,0) OP(1,1) OP(1,2) OP(1,3)
#define MFMA_BF16 __builtin_amdgcn_mfma_f32_16x16x32_bf16

__global__ __launch_bounds__(TPB, 2)
void vq_fused_kernel(const float* __restrict__ x,
                     const float* __restrict__ cb,
                     float* __restrict__ out_codes,
                     float* __restrict__ out_fidx,
                     float* __restrict__ out_idx,
                     float* __restrict__ out_dist,
                     int rows)
{
    __shared__ __align__(16) uint8_t s_buf[2 * BUFB];    // 69632 B; group A half is also A-stage area
    __shared__ float s_cq[2][NCHUNK];
    __shared__ float s_v1h[2][ROWS_PB], s_v2h[2][ROWS_PB];
    __shared__ int   s_k1h[2][ROWS_PB], s_k2h[2][ROWS_PB];
    __shared__ int   s_k1f[ROWS_PB];

    const int t    = threadIdx.x;
    const int lane = t & 63;
    const int w    = t >> 6;       // wave 0..7
    const int kh   = w >> 2;       // code-half 0/1
    const int wg   = w & 3;        // wave-in-group 0..3
    const int tg   = t & 255;      // thread-in-group 0..255
    const int ln   = lane & 15;
    const int quad = lane >> 4;
    const int rowblock = blockIdx.x * ROWS_PB;
    const int kh0      = kh * KHALF;

    // ---- stage x tile -> bf16 HI in s_buf (padded row-major), all 512 threads ----
    #pragma unroll 4
    for (int i = 0; i < 8; ++i) {
        int fid = t + i * TPB;            // float4 id in tile (4096)
        int row = fid >> 5;               // 0..127
        int kq  = fid & 31;               // float4 within row
        int grow = rowblock + row;
        grow = grow < rows ? grow : rows - 1;
        float4 v = ((const float4*)x)[(size_t)grow * 32 + kq];
        uint32_t p0 = bf16_rne(v.x) | (bf16_rne(v.y) << 16);
        uint32_t p1 = bf16_rne(v.z) | (bf16_rne(v.w) << 16);
        *(uint2*)(s_buf + row * BSTRIDE + kq * 8) = make_uint2(p0, p1);
    }
    __syncthreads();

    // ---- A-hi fragments -> registers (waves 0&4 share rows 0-31, etc.) ----
    const int arow0 = (wg * 32 + ln) * BSTRIDE;        // rowgroup 0
    const int arow1 = (wg * 32 + 16 + ln) * BSTRIDE;   // rowgroup 1
    bf16x8_t ah00, ah01, ah02, ah03, ah10, ah11, ah12, ah13;
    ah00 = *(const bf16x8_t*)(s_buf + arow0 + 0 * 64 + quad * 16);
    ah01 = *(const bf16x8_t*)(s_buf + arow0 + 1 * 64 + quad * 16);
    ah02 = *(const bf16x8_t*)(s_buf + arow0 + 2 * 64 + quad * 16);
    ah03 = *(const bf16x8_t*)(s_buf + arow0 + 3 * 64 + quad * 16);
    ah10 = *(const bf16x8_t*)(s_buf + arow1 + 0 * 64 + quad * 16);
    ah11 = *(const bf16x8_t*)(s_buf + arow1 + 1 * 64 + quad * 16);
    ah12 = *(const bf16x8_t*)(s_buf + arow1 + 2 * 64 + quad * 16);
    ah13 = *(const bf16x8_t*)(s_buf + arow1 + 3 * 64 + quad * 16);
    __syncthreads();

    // ---- stage x tile -> bf16 LO ----
    #pragma unroll 4
    for (int i = 0; i < 8; ++i) {
        int fid = t + i * TPB;
        int row = fid >> 5;
        int kq  = fid & 31;
        int grow = rowblock + row;
        grow = grow < rows ? grow : rows - 1;
        float4 v = ((const float4*)x)[(size_t)grow * 32 + kq];
        uint32_t p0 = bf16_rne(v.x - bf16_hi_f(v.x)) | (bf16_rne(v.y - bf16_hi_f(v.y)) << 16);
        uint32_t p1 = bf16_rne(v.z - bf16_hi_f(v.z)) | (bf16_rne(v.w - bf16_hi_f(v.w)) << 16);
        *(uint2*)(s_buf + row * BSTRIDE + kq * 8) = make_uint2(p0, p1);
    }
    __syncthreads();

    bf16x8_t al00, al01, al02, al03, al10, al11, al12, al13;
    al00 = *(const bf16x8_t*)(s_buf + arow0 + 0 * 64 + quad * 16);
    al01 = *(const bf16x8_t*)(s_buf + arow0 + 1 * 64 + quad * 16);
    al02 = *(const bf16x8_t*)(s_buf + arow0 + 2 * 64 + quad * 16);
    al03 = *(const bf16x8_t*)(s_buf + arow0 + 3 * 64 + quad * 16);
    al10 = *(const bf16x8_t*)(s_buf + arow1 + 0 * 64 + quad * 16);
    al11 = *(const bf16x8_t*)(s_buf + arow1 + 1 * 64 + quad * 16);
    al12 = *(const bf16x8_t*)(s_buf + arow1 + 2 * 64 + quad * 16);
    al13 = *(const bf16x8_t*)(s_buf + arow1 + 3 * 64 + quad * 16);
    __syncthreads();

    // ---- per-lane top-2 state (8 row-slots) ----
#define DECL(g,r) float v1_##g##r = INFINITY, v2_##g##r = INFINITY; int k1_##g##r = 0, k2_##g##r = 0;
    SLOTS(DECL)
#undef DECL

    uint8_t* const gbuf = s_buf + kh * BUFB;   // this group's B buffer

    #pragma unroll 1
    for (int chn = 0; chn < NCHUNKS_H; ++chn) {
        const int kbase = kh0 + chn * NCHUNK;
        // ---- stage B chunk from RAW fp32 codebook (group-local, 256 threads):
        //      inline bf16 hi/lo convert (bit-identical exprs, R5/R7-validated)
        //      + coarse ||c||^2 via 16-lane tree reduce (selection-only). ----
        #pragma unroll
        for (int i = 0; i < 4; ++i) {
            int uid  = tg + i * 256;         // slot id (1024): code*16 + g
            int code = uid >> 4, g = uid & 15;
            const float4* src = (const float4*)(cb + (size_t)(kbase + code) * C) + g * 2;
            float4 v0 = src[0], v1 = src[1];
            uint32_t h0 = bf16_rne(v0.x) | (bf16_rne(v0.y) << 16);
            uint32_t h1 = bf16_rne(v0.z) | (bf16_rne(v0.w) << 16);
            uint32_t h2 = bf16_rne(v1.x) | (bf16_rne(v1.y) << 16);
            uint32_t h3 = bf16_rne(v1.z) | (bf16_rne(v1.w) << 16);
            uint32_t l0 = bf16_rne(v0.x - bf16_hi_f(v0.x)) | (bf16_rne(v0.y - bf16_hi_f(v0.y)) << 16);
            uint32_t l1 = bf16_rne(v0.z - bf16_hi_f(v0.z)) | (bf16_rne(v0.w - bf16_hi_f(v0.w)) << 16);
            uint32_t l2 = bf16_rne(v1.x - bf16_hi_f(v1.x)) | (bf16_rne(v1.y - bf16_hi_f(v1.y)) << 16);
            uint32_t l3 = bf16_rne(v1.z - bf16_hi_f(v1.z)) | (bf16_rne(v1.w - bf16_hi_f(v1.w)) << 16);
            *(uint4*)(gbuf + code * BSTRIDE + g * 16)          = make_uint4(h0, h1, h2, h3);
            *(uint4*)(gbuf + BHALF + code * BSTRIDE + g * 16)  = make_uint4(l0, l1, l2, l3);
            float ps = ((v0.x * v0.x + v0.y * v0.y) + (v0.z * v0.z + v0.w * v0.w))
                     + ((v1.x * v1.x + v1.y * v1.y) + (v1.z * v1.z + v1.w * v1.w));
            ps += __shfl_xor(ps, 1, 16);
            ps += __shfl_xor(ps, 2, 16);
            ps += __shfl_xor(ps, 4, 16);
            ps += __shfl_xor(ps, 8, 16);
            if (g == 0) s_cq[kh][code] = ps;
        }
        __syncthreads();

        const uint8_t* bbase = gbuf + (size_t)ln * BSTRIDE + quad * 16;
        #pragma unroll
        for (int ct = 0; ct < 4; ++ct) {
            const uint8_t* bh_p = bbase + (size_t)ct * 16 * BSTRIDE;
            const uint8_t* bl_p = bh_p + BHALF;
            f32x4_t acc0 = {0.f, 0.f, 0.f, 0.f};
            f32x4_t acc1 = {0.f, 0.f, 0.f, 0.f};
#define KSTEP(kk) { \
            bf16x8_t bh = *(const bf16x8_t*)(bh_p + kk * 64); \
            bf16x8_t bl = *(const bf16x8_t*)(bl_p + kk * 64); \
            acc0 = MFMA_BF16(ah0##kk, bh, acc0, 0, 0, 0); \
            acc0 = MFMA_BF16(al0##kk, bh, acc0, 0, 0, 0); \
            acc0 = MFMA_BF16(ah0##kk, bl, acc0, 0, 0, 0); \
            acc1 = MFMA_BF16(ah1##kk, bh, acc1, 0, 0, 0); \
            acc1 = MFMA_BF16(al1##kk, bh, acc1, 0, 0, 0); \
            acc1 = MFMA_BF16(ah1##kk, bl, acc1, 0, 0, 0); }
            KSTEP(0) KSTEP(1) KSTEP(2) KSTEP(3)
#undef KSTEP
            const float cqv = s_cq[kh][ct * 16 + ln];
            const int   kc  = kbase + ct * 16 + ln;
#define UPD(g,r) { \
            float s_ = fmaf(-2.0f, (g ? acc1 : acc0)[r], cqv); \
            bool c1_ = s_ < v1_##g##r; \
            bool c2_ = s_ < v2_##g##r; \
            v2_##g##r = c1_ ? v1_##g##r : (c2_ ? s_ : v2_##g##r); \
            k2_##g##r = c1_ ? k1_##g##r : (c2_ ? kc : k2_##g##r); \
            v1_##g##r = c1_ ? s_ : v1_##g##r; \
            k1_##g##r = c1_ ? kc : k1_##g##r; }
            SLOTS(UPD)
#undef UPD
        }
        __syncthreads();
    }

    // ---- butterfly merge across the 16 lanes of each col-group ----
    for (int m_ = 1; m_ <= 8; m_ <<= 1) {
#define MRG(g,r) { \
        float ov1 = __shfl_xor(v1_##g##r, m_, 16); int ok1 = __shfl_xor(k1_##g##r, m_, 16); \
        float ov2 = __shfl_xor(v2_##g##r, m_, 16); int ok2 = __shfl_xor(k2_##g##r, m_, 16); \
        if (ov1 < v1_##g##r || (ov1 == v1_##g##r && ok1 < k1_##g##r)) { \
            if (v1_##g##r < ov2 || (v1_##g##r == ov2 && k1_##g##r < ok2)) { v2_##g##r = v1_##g##r; k2_##g##r = k1_##g##r; } \
            else { v2_##g##r = ov2; k2_##g##r = ok2; } \
            v1_##g##r = ov1; k1_##g##r = ok1; \
        } else if (ov1 < v2_##g##r || (ov1 == v2_##g##r && ok1 < k2_##g##r)) { \
            v2_##g##r = ov1; k2_##g##r = ok1; \
        } }
        SLOTS(MRG)
#undef MRG
    }
    // ---- lane 0 of each col-group writes its half's per-row top-2 ----
    if (ln == 0) {
#define WRT(g,r) { int rloc = wg * 32 + g * 16 + quad * 4 + r; \
        s_v1h[kh][rloc] = v1_##g##r; s_v2h[kh][rloc] = v2_##g##r; \
        s_k1h[kh][rloc] = k1_##g##r; s_k2h[kh][rloc] = k2_##g##r; }
        SLOTS(WRT)
#undef WRT
    }
    __syncthreads();

    // ---- merge halves + finalize (threads 0..127, one per row) ----
    if (t < ROWS_PB) {
        int rowg = rowblock + t;
        const bool valid = rowg < rows;
        rowg = valid ? rowg : rows - 1;

        float av1 = s_v1h[0][t], av2 = s_v2h[0][t];
        int   ak1 = s_k1h[0][t], ak2 = s_k2h[0][t];
        float bv1 = s_v1h[1][t], bv2 = s_v2h[1][t];
        int   bk1 = s_k1h[1][t], bk2 = s_k2h[1][t];

        // merge (R4-validated comparator; half-0 indices < half-1 indices,
        // so index-tiebreak == sequential-scan order)
        float v1, v2; int k1, k2;
        if (bv1 < av1 || (bv1 == av1 && bk1 < ak1)) {
            v1 = bv1; k1 = bk1;
            if (av1 < bv2 || (av1 == bv2 && ak1 < bk2)) { v2 = av1; k2 = ak1; }
            else                                        { v2 = bv2; k2 = bk2; }
        } else {
            v1 = av1; k1 = ak1;
            if (bv1 < av2 || (bv1 == av2 && bk1 < ak2)) { v2 = bv1; k2 = bk1; }
            else                                        { v2 = av2; k2 = ak2; }
        }

        const float* xr = x + (size_t)rowg * C;

        // rs in R1 float4 order
        float sx = 0.f, sy = 0.f, sz = 0.f, sw = 0.f;
        {
            const float4* xp = (const float4*)xr;
            #pragma unroll
            for (int i = 0; i < C / 4; ++i) {
                float4 v = xp[i];
                sx += v.x * v.x; sy += v.y * v.y;
                sz += v.z * v.z; sw += v.w * v.w;
            }
        }
        const float rs = (sx + sy) + (sz + sw);

        bool switched = false;
        double qwin = 0.0;
        if (v2 - v1 < EPS_TRIG) {
            const float* c1p = cb + (size_t)k1 * C;
            const float* c2p = cb + (size_t)k2 * C;
            double dot1 = 0.0, cq1 = 0.0, dot2 = 0.0, cq2 = 0.0;
            #pragma unroll 8
            for (int c = 0; c < C; ++c) {
                const double xc  = (double)xr[c];
                const double cv1 = (double)c1p[c];
                const double cv2 = (double)c2p[c];
                dot1 += xc * cv1;  cq1 += cv1 * cv1;
                dot2 += xc * cv2;  cq2 += cv2 * cv2;
            }
            const double q1 = cq1 - 2.0 * dot1;
            const double q2 = cq2 - 2.0 * dot2;
            if (q2 < q1 || (q2 == q1 && k2 < k1)) { k1 = k2; switched = true; qwin = q2; }
        }

        // exact fp32 distance for the final k1 (R1 chain order) + inline
        // ||c_k1||^2 in the exact cbsq float4-chain order (R5/R7-validated)
        {
            const float4* c1p4 = (const float4*)(cb + (size_t)k1 * C);
            float a = 0.f;
            float qx = 0.f, qy = 0.f, qz = 0.f, qw = 0.f;
            #pragma unroll
            for (int i = 0; i < C / 4; ++i) {
                float4 cv = c1p4[i];
                float4 xv = ((const float4*)xr)[i];
                a = fmaf(xv.x, cv.x, a); a = fmaf(xv.y, cv.y, a);
                a = fmaf(xv.z, cv.z, a); a = fmaf(xv.w, cv.w, a);
                qx += cv.x * cv.x; qy += cv.y * cv.y;
                qz += cv.z * cv.z; qw += cv.w * cv.w;
            }
            float d = (rs + ((qx + qy) + (qz + qw))) - 2.f * a;
            if (switched) d = (float)((double)rs + qwin);

            if (valid) {
                out_fidx[rowg] = (float)k1;
                out_idx[rowg]  = (float)k1;
                out_dist[rowg] = d;
            }
        }
        s_k1f[t] = k1;   // final index for the gather
    }
    __syncthreads();

    // ---- gather codes: 4 threads per row (512 threads / 128 rows) ----
    {
        const int r   = t >> 2;
        const int sub = t & 3;
        const int rowg = rowblock + r;
        if (rowg < rows) {
            const int k1 = s_k1f[r];
            const float4* src = (const float4*)(cb + (size_t)k1 * C) + sub * 8;
            float4*       dst = (float4*)(out_codes + (size_t)rowg * C) + sub * 8;
            #pragma unroll
            for (int i = 0; i < 8; ++i) dst[i] = src[i];
        }
    }
}

extern "C" void kernel_launch(void* const* d_in, const int* in_sizes, int n_in,
                              void* d_out, int out_size, void* d_ws, size_t ws_size,
                              hipStream_t stream) {
    const float* x  = (const float*)d_in[0];
    const float* cb = (const float*)d_in[1];
    const int rows = in_sizes[0] / C;   // 65536

    float* out       = (float*)d_out;
    float* out_codes = out;                          // rows*C
    float* out_fidx  = out + (size_t)rows * C;       // rows
    float* out_idx   = out_fidx + rows;              // rows
    float* out_dist  = out_idx + rows;               // rows

    const int grid = (rows + ROWS_PB - 1) / ROWS_PB;   // 512
    vq_fused_kernel<<<grid, TPB, 0, stream>>>(x, cb, out_codes, out_fidx,
                                              out_idx, out_dist, rows);
}

// Round 11
// 170.510 us; speedup vs baseline: 1.8342x; 1.1878x over previous
//
#include <hip/hip_runtime.h>
#include <math.h>
#include <stdint.h>

#define C        128
#define KCODES   1024
#define TPB      256
#define ROWS_PB  128                  // rows per block
#define NCHUNK   64                   // codes per LDS chunk
#define NCHUNKS  (KCODES / NCHUNK)    // 16
#define BSTRIDE  272                  // padded row stride (bytes) = 128*2 + 16
#define BHALF    (NCHUNK * BSTRIDE)   // byte offset of B LO plane = 17408
#define ALO_OFF  (ROWS_PB * BSTRIDE)  // byte offset of A LO plane = 34816
#define EPS_TRIG 0.25f

typedef __attribute__((ext_vector_type(8))) short bf16x8_t;
typedef __attribute__((ext_vector_type(4))) float f32x4_t;

static __device__ __forceinline__ uint32_t bf16_rne(float f) {
    uint32_t u = __float_as_uint(f);
    return (u + 0x7FFFu + ((u >> 16) & 1u)) >> 16;
}
static __device__ __forceinline__ float bf16_hi_f(float f) {
    return __uint_as_float(bf16_rne(f) << 16);
}

// ---------------- prep (fused): split codebook into bf16 hi/lo + ||c||^2 ----------------
// (R2-validated; kernel-sum cost ~5us. Per-block inline convert costs ~24us
// VALU -- R7 measured -- so a separate prep kernel is the right trade.)
__global__ void cb_prep_kernel(const float* __restrict__ cb,
                               uint16_t* __restrict__ cbh,
                               uint16_t* __restrict__ cbl,
                               float* __restrict__ cbsq) {
    const int i = blockIdx.x * blockDim.x + threadIdx.x;
    if (i < KCODES * C) {
        float f = cb[i];
        uint32_t h = bf16_rne(f);
        float lo = f - __uint_as_float(h << 16);
        cbh[i] = (uint16_t)h;
        cbl[i] = (uint16_t)bf16_rne(lo);
    }
    if (i < KCODES) {
        const float4* cp = (const float4*)(cb + (size_t)i * C);
        float sx = 0.f, sy = 0.f, sz = 0.f, sw = 0.f;
        #pragma unroll
        for (int j = 0; j < C / 4; ++j) {
            float4 v = cp[j];
            sx += v.x * v.x; sy += v.y * v.y;
            sz += v.z * v.z; sw += v.w * v.w;
        }
        cbsq[i] = (sx + sy) + (sz + sw);
    }
}

// ============================================================================
// Main kernel (R1 base, grid 512 = 2 blocks/CU pinned):
//   - ONE-PASS A-stage: x loaded once, hi->buf0 lo->buf1 (bit-identical
//     exprs); 2 barriers instead of 4, no x reload.
//   - kk-SPLIT ACCUMULATORS: 8 independent 3-deep MFMA chains (was 2 chains
//     of 12 dependent MFMAs) -- removes matrix-pipe latency stall at the
//     2-waves/SIMD occupancy the grid pins us to. Accumulation-order change
//     is output-safe: fp64 near-tie rescan + exact finalize protect outputs.
//   - __launch_bounds__(256,2): grid caps residency at 2 blocks/CU anyway,
//     so give the allocator register slack (R3/R8 lesson: tight caps spill).
// ============================================================================
#define SLOTS(OP) OP(0,0) OP(0,1) OP(0,2) OP(0,3) OP(1,0) OP(1,1) OP(1,2) OP(1,3)
#define MFMA_BF16 __builtin_amdgcn_mfma_f32_16x16x32_bf16

__global__ __launch_bounds__(TPB, 2)
void vq_mfma_kernel(const float* __restrict__ x,
                    const float* __restrict__ cb,
                    const uint16_t* __restrict__ cbh,
                    const uint16_t* __restrict__ cbl,
                    const float* __restrict__ cq,
                    float* __restrict__ out_codes,
                    float* __restrict__ out_fidx,
                    float* __restrict__ out_idx,
                    float* __restrict__ out_dist,
                    int rows)
{
    __shared__ __align__(16) uint8_t s_buf[2 * ALO_OFF];  // 69632 B: A hi|lo, then B chunk in [0,34816)
    __shared__ float s_cq[NCHUNK];
    __shared__ float s_v1[ROWS_PB], s_v2[ROWS_PB];
    __shared__ int   s_k1[ROWS_PB], s_k2[ROWS_PB];

    const int t    = threadIdx.x;
    const int lane = t & 63;
    const int w    = t >> 6;       // wave 0..3
    const int ln   = lane & 15;
    const int quad = lane >> 4;
    const int rowblock = blockIdx.x * ROWS_PB;

    // ---- ONE-PASS stage: x tile -> bf16 HI (buf0) + LO (buf1) ----
    #pragma unroll 4
    for (int i = 0; i < 16; ++i) {
        int fid = t + i * TPB;            // float4 id in tile (4096)
        int row = fid >> 5;               // 0..127
        int kq  = fid & 31;               // float4 within row
        int grow = rowblock + row;
        grow = grow < rows ? grow : rows - 1;
        float4 v = ((const float4*)x)[(size_t)grow * 32 + kq];
        uint32_t p0 = bf16_rne(v.x) | (bf16_rne(v.y) << 16);
        uint32_t p1 = bf16_rne(v.z) | (bf16_rne(v.w) << 16);
        uint32_t q0 = bf16_rne(v.x - bf16_hi_f(v.x)) | (bf16_rne(v.y - bf16_hi_f(v.y)) << 16);
        uint32_t q1 = bf16_rne(v.z - bf16_hi_f(v.z)) | (bf16_rne(v.w - bf16_hi_f(v.w)) << 16);
        *(uint2*)(s_buf + row * BSTRIDE + kq * 8)           = make_uint2(p0, p1);
        *(uint2*)(s_buf + ALO_OFF + row * BSTRIDE + kq * 8) = make_uint2(q0, q1);
    }
    __syncthreads();

    // ---- A hi+lo fragments -> registers (live for the whole kernel) ----
    const int arow0 = (w * 32 + ln) * BSTRIDE;        // rowgroup 0
    const int arow1 = (w * 32 + 16 + ln) * BSTRIDE;   // rowgroup 1
    bf16x8_t ah00, ah01, ah02, ah03, ah10, ah11, ah12, ah13;
    bf16x8_t al00, al01, al02, al03, al10, al11, al12, al13;
    ah00 = *(const bf16x8_t*)(s_buf + arow0 + 0 * 64 + quad * 16);
    ah01 = *(const bf16x8_t*)(s_buf + arow0 + 1 * 64 + quad * 16);
    ah02 = *(const bf16x8_t*)(s_buf + arow0 + 2 * 64 + quad * 16);
    ah03 = *(const bf16x8_t*)(s_buf + arow0 + 3 * 64 + quad * 16);
    ah10 = *(const bf16x8_t*)(s_buf + arow1 + 0 * 64 + quad * 16);
    ah11 = *(const bf16x8_t*)(s_buf + arow1 + 1 * 64 + quad * 16);
    ah12 = *(const bf16x8_t*)(s_buf + arow1 + 2 * 64 + quad * 16);
    ah13 = *(const bf16x8_t*)(s_buf + arow1 + 3 * 64 + quad * 16);
    al00 = *(const bf16x8_t*)(s_buf + ALO_OFF + arow0 + 0 * 64 + quad * 16);
    al01 = *(const bf16x8_t*)(s_buf + ALO_OFF + arow0 + 1 * 64 + quad * 16);
    al02 = *(const bf16x8_t*)(s_buf + ALO_OFF + arow0 + 2 * 64 + quad * 16);
    al03 = *(const bf16x8_t*)(s_buf + ALO_OFF + arow0 + 3 * 64 + quad * 16);
    al10 = *(const bf16x8_t*)(s_buf + ALO_OFF + arow1 + 0 * 64 + quad * 16);
    al11 = *(const bf16x8_t*)(s_buf + ALO_OFF + arow1 + 1 * 64 + quad * 16);
    al12 = *(const bf16x8_t*)(s_buf + ALO_OFF + arow1 + 2 * 64 + quad * 16);
    al13 = *(const bf16x8_t*)(s_buf + ALO_OFF + arow1 + 3 * 64 + quad * 16);
    __syncthreads();

    // ---- per-lane top-2 state (8 row-slots) ----
#define DECL(g,r) float v1_##g##r = INFINITY, v2_##g##r = INFINITY; int k1_##g##r = 0, k2_##g##r = 0;
    SLOTS(DECL)
#undef DECL

    // hoisted chunk-invariant staging addresses
    int lds_off[4];
    #pragma unroll
    for (int i = 0; i < 4; ++i) {
        int uid = t + i * TPB;
        lds_off[i] = (uid >> 4) * BSTRIDE + (uid & 15) * 16;
    }
    const uint4* gh = (const uint4*)cbh + t;   // bumped by NCHUNK*16 per chunk
    const uint4* gl = (const uint4*)cbl + t;

    #pragma unroll 1
    for (int chn = 0; chn < NCHUNKS; ++chn) {
        const int kbase = chn * NCHUNK;
        // stage B chunk: 64 codes hi + lo (padded rows)
        #pragma unroll
        for (int i = 0; i < 4; ++i) {
            uint4 dh = gh[i * TPB];
            uint4 dl = gl[i * TPB];
            *(uint4*)(s_buf + lds_off[i])          = dh;
            *(uint4*)(s_buf + BHALF + lds_off[i])  = dl;
        }
        gh += NCHUNK * 16;
        gl += NCHUNK * 16;
        if (t < NCHUNK) s_cq[t] = cq[kbase + t];
        __syncthreads();

        const uint8_t* bbase = s_buf + (size_t)ln * BSTRIDE + quad * 16;
        #pragma unroll
        for (int ct = 0; ct < 4; ++ct) {
            const uint8_t* bh_p = bbase + (size_t)ct * 16 * BSTRIDE;
            const uint8_t* bl_p = bh_p + BHALF;
            // 8 independent accumulator chains (g x kk), 3-deep each
            f32x4_t a00 = {0,0,0,0}, a01 = {0,0,0,0}, a02 = {0,0,0,0}, a03 = {0,0,0,0};
            f32x4_t a10 = {0,0,0,0}, a11 = {0,0,0,0}, a12 = {0,0,0,0}, a13 = {0,0,0,0};
#define KSTEP(kk) { \
            bf16x8_t bh = *(const bf16x8_t*)(bh_p + kk * 64); \
            bf16x8_t bl = *(const bf16x8_t*)(bl_p + kk * 64); \
            a0##kk = MFMA_BF16(ah0##kk, bh, a0##kk, 0, 0, 0); \
            a0##kk = MFMA_BF16(al0##kk, bh, a0##kk, 0, 0, 0); \
            a0##kk = MFMA_BF16(ah0##kk, bl, a0##kk, 0, 0, 0); \
            a1##kk = MFMA_BF16(ah1##kk, bh, a1##kk, 0, 0, 0); \
            a1##kk = MFMA_BF16(al1##kk, bh, a1##kk, 0, 0, 0); \
            a1##kk = MFMA_BF16(ah1##kk, bl, a1##kk, 0, 0, 0); }
            KSTEP(0) KSTEP(1) KSTEP(2) KSTEP(3)
#undef KSTEP
            const f32x4_t sum0 = (a00 + a01) + (a02 + a03);
            const f32x4_t sum1 = (a10 + a11) + (a12 + a13);
            const float cqv = s_cq[ct * 16 + ln];
            const int   kc  = kbase + ct * 16 + ln;
#define UPD(g,r) { \
            float s_ = fmaf(-2.0f, (g ? sum1[r] : sum0[r]), cqv); \
            bool c1_ = s_ < v1_##g##r; \
            bool c2_ = s_ < v2_##g##r; \
            v2_##g##r = c1_ ? v1_##g##r : (c2_ ? s_ : v2_##g##r); \
            k2_##g##r = c1_ ? k1_##g##r : (c2_ ? kc : k2_##g##r); \
            v1_##g##r = c1_ ? s_ : v1_##g##r; \
            k1_##g##r = c1_ ? kc : k1_##g##r; }
            SLOTS(UPD)
#undef UPD
        }
        __syncthreads();
    }

    // ---- butterfly merge across the 16 lanes of each col-group ----
    for (int m_ = 1; m_ <= 8; m_ <<= 1) {
#define MRG(g,r) { \
        float ov1 = __shfl_xor(v1_##g##r, m_, 16); int ok1 = __shfl_xor(k1_##g##r, m_, 16); \
        float ov2 = __shfl_xor(v2_##g##r, m_, 16); int ok2 = __shfl_xor(k2_##g##r, m_, 16); \
        if (ov1 < v1_##g##r || (ov1 == v1_##g##r && ok1 < k1_##g##r)) { \
            if (v1_##g##r < ov2 || (v1_##g##r == ov2 && k1_##g##r < ok2)) { v2_##g##r = v1_##g##r; k2_##g##r = k1_##g##r; } \
            else { v2_##g##r = ov2; k2_##g##r = ok2; } \
            v1_##g##r = ov1; k1_##g##r = ok1; \
        } else if (ov1 < v2_##g##r || (ov1 == v2_##g##r && ok1 < k2_##g##r)) { \
            v2_##g##r = ov1; k2_##g##r = ok1; \
        } }
        SLOTS(MRG)
#undef MRG
    }
    if (ln == 0) {
#define WRT(g,r) { int rloc = w * 32 + g * 16 + quad * 4 + r; \
        s_v1[rloc] = v1_##g##r; s_v2[rloc] = v2_##g##r; \
        s_k1[rloc] = k1_##g##r; s_k2[rloc] = k2_##g##r; }
        SLOTS(WRT)
#undef WRT
    }
    __syncthreads();

    // ---- per-row finalize: fp32 R1-order distance + fp64 near-tie re-decide ----
    if (t < ROWS_PB) {
        int rowg = rowblock + t;
        const bool valid = rowg < rows;
        rowg = valid ? rowg : rows - 1;
        float v1 = s_v1[t], v2 = s_v2[t];
        int k1 = s_k1[t], k2 = s_k2[t];
        const float* xr = x + (size_t)rowg * C;

        // rs in R1 float4 order
        float sx = 0.f, sy = 0.f, sz = 0.f, sw = 0.f;
        {
            const float4* xp = (const float4*)xr;
            #pragma unroll
            for (int i = 0; i < C / 4; ++i) {
                float4 v = xp[i];
                sx += v.x * v.x; sy += v.y * v.y;
                sz += v.z * v.z; sw += v.w * v.w;
            }
        }
        const float rs = (sx + sy) + (sz + sw);

        bool switched = false;
        double qwin = 0.0;
        if (v2 - v1 < EPS_TRIG) {
            const float* c1p = cb + (size_t)k1 * C;
            const float* c2p = cb + (size_t)k2 * C;
            double dot1 = 0.0, cq1 = 0.0, dot2 = 0.0, cq2 = 0.0;
            #pragma unroll 8
            for (int c = 0; c < C; ++c) {
                const double xc  = (double)xr[c];
                const double cv1 = (double)c1p[c];
                const double cv2 = (double)c2p[c];
                dot1 += xc * cv1;  cq1 += cv1 * cv1;
                dot2 += xc * cv2;  cq2 += cv2 * cv2;
            }
            const double q1 = cq1 - 2.0 * dot1;
            const double q2 = cq2 - 2.0 * dot2;
            if (q2 < q1 || (q2 == q1 && k2 < k1)) { k1 = k2; switched = true; qwin = q2; }
        }

        // exact fp32 distance for the final k1 (R1 chain order)
        const float* c1p = cb + (size_t)k1 * C;
        float a = 0.f;
        #pragma unroll 16
        for (int c = 0; c < C; ++c) a = fmaf(xr[c], c1p[c], a);
        float d = (rs + cq[k1]) - 2.f * a;
        if (switched) d = (float)((double)rs + qwin);

        if (valid) {
            out_fidx[rowg] = (float)k1;
            out_idx[rowg]  = (float)k1;
            out_dist[rowg] = d;
        }
        s_k1[t] = k1;   // final index for the gather
    }
    __syncthreads();

    // ---- gather codes: 2 threads per row ----
    {
        const int r    = t >> 1;
        const int half = t & 1;
        const int rowg = rowblock + r;
        if (rowg < rows) {
            const int k1 = s_k1[r];
            const float4* src = (const float4*)(cb + (size_t)k1 * C) + half * 16;
            float4*       dst = (float4*)(out_codes + (size_t)rowg * C) + half * 16;
            #pragma unroll
            for (int i = 0; i < 16; ++i) dst[i] = src[i];
        }
    }
}

// ---------------- fallback (R1 kernel, needs no workspace) ----------------
__global__ __launch_bounds__(TPB, 1)
void vq_nearest_fallback(const float* __restrict__ x,
                         const float* __restrict__ cb,
                         float* __restrict__ out_codes,
                         float* __restrict__ out_fidx,
                         float* __restrict__ out_idx,
                         float* __restrict__ out_dist,
                         int rows)
{
    __shared__ float s_cbsq[KCODES];
    const int t = threadIdx.x;
    for (int k = t; k < KCODES; k += TPB) {
        const float4* cp = (const float4*)(cb + (size_t)k * C);
        float sx = 0.f, sy = 0.f, sz = 0.f, sw = 0.f;
        #pragma unroll
        for (int i = 0; i < C / 4; ++i) {
            float4 v = cp[i];
            sx += v.x * v.x; sy += v.y * v.y; sz += v.z * v.z; sw += v.w * v.w;
        }
        s_cbsq[k] = (sx + sy) + (sz + sw);
    }
    __syncthreads();
    const int row = blockIdx.x * TPB + t;
    if (row >= rows) return;
    float xr[C];
    {
        const float4* xp = (const float4*)(x + (size_t)row * C);
        #pragma unroll
        for (int i = 0; i < C / 4; ++i) {
            float4 v = xp[i];
            xr[4*i+0] = v.x; xr[4*i+1] = v.y; xr[4*i+2] = v.z; xr[4*i+3] = v.w;
        }
    }
    float rs;
    {
        float sx = 0.f, sy = 0.f, sz = 0.f, sw = 0.f;
        #pragma unroll
        for (int i = 0; i < C / 4; ++i) {
            sx += xr[4*i+0]*xr[4*i+0]; sy += xr[4*i+1]*xr[4*i+1];
            sz += xr[4*i+2]*xr[4*i+2]; sw += xr[4*i+3]*xr[4*i+3];
        }
        rs = (sx + sy) + (sz + sw);
    }
    float v1 = INFINITY, v2 = INFINITY; int k1 = 0, k2 = 0;
    #pragma unroll 1
    for (int k0 = 0; k0 < KCODES; k0 += 4) {
        const float* c0 = cb + (size_t)k0 * C;
        float a0 = 0.f, a1 = 0.f, a2 = 0.f, a3 = 0.f;
        #pragma unroll
        for (int c = 0; c < C; ++c) {
            const float xc = xr[c];
            a0 = fmaf(xc, c0[c], a0);
            a1 = fmaf(xc, c0[C + c], a1);
            a2 = fmaf(xc, c0[2*C + c], a2);
            a3 = fmaf(xc, c0[3*C + c], a3);
        }
        const float d0 = (rs + s_cbsq[k0+0]) - 2.f * a0;
        const float d1 = (rs + s_cbsq[k0+1]) - 2.f * a1;
        const float d2 = (rs + s_cbsq[k0+2]) - 2.f * a2;
        const float d3 = (rs + s_cbsq[k0+3]) - 2.f * a3;
        #define UPDF(dv, ki)                                                 \
            if ((dv) < v1)      { v2 = v1; k2 = k1; v1 = (dv); k1 = (ki); } \
            else if ((dv) < v2) { v2 = (dv); k2 = (ki); }
        UPDF(d0, k0+0); UPDF(d1, k0+1); UPDF(d2, k0+2); UPDF(d3, k0+3);
        #undef UPDF
    }
    if (v2 - v1 < 0.125f) {
        const float* c1p = cb + (size_t)k1 * C;
        const float* c2p = cb + (size_t)k2 * C;
        double dot1 = 0.0, cq1 = 0.0, dot2 = 0.0, cq2 = 0.0;
        #pragma unroll 8
        for (int c = 0; c < C; ++c) {
            const double xc = (double)xr[c];
            const double cv1 = (double)c1p[c];
            const double cv2 = (double)c2p[c];
            dot1 += xc * cv1; cq1 += cv1 * cv1;
            dot2 += xc * cv2; cq2 += cv2 * cv2;
        }
        const double q1 = cq1 - 2.0 * dot1;
        const double q2 = cq2 - 2.0 * dot2;
        if (q2 < q1 || (q2 == q1 && k2 < k1)) { k1 = k2; v1 = (float)((double)rs + q2); }
    }
    {
        const float4* src = (const float4*)(cb + (size_t)k1 * C);
        float4* dst = (float4*)(out_codes + (size_t)row * C);
        #pragma unroll
        for (int i = 0; i < C / 4; ++i) dst[i] = src[i];
        out_fidx[row] = (float)k1;
        out_idx[row]  = (float)k1;
        out_dist[row] = v1;
    }
}

extern "C" void kernel_launch(void* const* d_in, const int* in_sizes, int n_in,
                              void* d_out, int out_size, void* d_ws, size_t ws_size,
                              hipStream_t stream) {
    const float* x  = (const float*)d_in[0];
    const float* cb = (const float*)d_in[1];
    const int rows = in_sizes[0] / C;   // 65536

    float* out       = (float*)d_out;
    float* out_codes = out;                          // rows*C
    float* out_fidx  = out + (size_t)rows * C;       // rows
    float* out_idx   = out_fidx + rows;              // rows
    float* out_dist  = out_idx + rows;               // rows

    // workspace layout
    const size_t cbh_off = 0;
    const size_t cbl_off = (size_t)KCODES * C * sizeof(uint16_t);      // 256 KB
    const size_t cq_off  = cbl_off * 2;                                // 512 KB
    const size_t need    = cq_off + KCODES * sizeof(float);

    if (ws_size >= need) {
        uint16_t* cbh = (uint16_t*)((char*)d_ws + cbh_off);
        uint16_t* cbl = (uint16_t*)((char*)d_ws + cbl_off);
        float*    cq  = (float*)((char*)d_ws + cq_off);

        cb_prep_kernel<<<(KCODES * C + TPB - 1) / TPB, TPB, 0, stream>>>(cb, cbh, cbl, cq);

        const int grid = (rows + ROWS_PB - 1) / ROWS_PB;   // 512
        vq_mfma_kernel<<<grid, TPB, 0, stream>>>(x, cb, cbh, cbl, cq,
                                                 out_codes, out_fidx, out_idx,
                                                 out_dist, rows);
    } else {
        const int rowblocks = (rows + TPB - 1) / TPB;
        vq_nearest_fallback<<<rowblocks, TPB, 0, stream>>>(x, cb, out_codes, out_fidx,
                                                           out_idx, out_dist, rows);
    }
}